// Round 3
// baseline (2869.506 us; speedup 1.0000x reference)
//
#include <hip/hip_runtime.h>
#include <hip/hip_bf16.h>
#include <stdint.h>

typedef __bf16 bf16x8 __attribute__((ext_vector_type(8)));
typedef float  f32x4  __attribute__((ext_vector_type(4)));
typedef uint32_t u32x4 __attribute__((ext_vector_type(4)));

#define BAR()  asm volatile("s_waitcnt lgkmcnt(0)\n\ts_barrier" ::: "memory")

static __device__ __forceinline__ float sigm(float x) {
  return __builtin_amdgcn_rcpf(1.0f + __builtin_amdgcn_exp2f(x * -1.4426950408889634f));
}
static __device__ __forceinline__ float tanh_fast(float x) {
  // tanh(x) = 1 - 2/(exp2(2x*log2e)+1); saturates correctly via exp2->inf/0
  return 1.0f - 2.0f * __builtin_amdgcn_rcpf(1.0f + __builtin_amdgcn_exp2f(x * 2.8853900817779268f));
}
static __device__ __forceinline__ unsigned short f2bf(float f) {
  return __builtin_bit_cast(unsigned short, (__bf16)f);
}
static __device__ __forceinline__ float bf2f(unsigned short u) {
  union { uint32_t i; float f; } v; v.i = ((uint32_t)u) << 16; return v.f;
}
static __device__ __forceinline__ void async16(const float* g, float* l) {
  __builtin_amdgcn_global_load_lds((__attribute__((address_space(1))) void*)g,
                                   (__attribute__((address_space(3))) void*)l, 16, 0, 0);
}
static __device__ __forceinline__ bf16x8 asbf(u32x4 v) {
  return __builtin_bit_cast(bf16x8, v);
}

// Persistent fused kernel: 64 WGs x 512 threads; WG owns 16 batch rows for all
// 512 timesteps. Wave wid owns h-cols wid*16..wid*16+15 and computes gate types
// i,f,g,o for those cols -> pointwise fully in registers. All weight fragments
// (Whh0, Wih1, Whh1, folded W0) pinned in AGPRs: 224 AGPRs/lane, persistent.
__global__ __launch_bounds__(512) __attribute__((amdgpu_waves_per_eu(2, 2)))
void fraud_lstm_kernel(
    const float* __restrict__ x,     const float* __restrict__ Wproj,
    const float* __restrict__ bproj, const float* __restrict__ Wih0,
    const float* __restrict__ Whh0,  const float* __restrict__ bih0,
    const float* __restrict__ bhh0,  const float* __restrict__ Wih1,
    const float* __restrict__ Whh1,  const float* __restrict__ bih1,
    const float* __restrict__ bhh1,  const float* __restrict__ Wh1,
    const float* __restrict__ bh1,   const float* __restrict__ Wh2,
    const float* __restrict__ bh2,   float* __restrict__ out)
{
  // LDS: 73728 + 2*8704 + 12288 + 4096 = 105 KB
  __shared__ unsigned short sW0[512*72];     // folded W0 = Wih0@Wproj, bf16 [gate row][f], stride 72
  __shared__ unsigned short sH0[2][16*136];  // h0 double buffer, bf16 [row][hcol], stride 136
  __shared__ unsigned short sH1[2][16*136];  // h1 double buffer
  __shared__ float sXf[3*1024];              // x tile triple buffer (16 rows x 64 f32), chunk-swizzled
  __shared__ float sB0[512];                 // bias0 = bih0+bhh0+Wih0@bproj
  __shared__ float sB1[512];                 // bias1 = bih1+bhh1

  const int tid  = threadIdx.x;
  const int lane = tid & 63;
  const int wid  = tid >> 6;      // 8 waves
  const int lr   = lane & 15;     // fragment row/col lane index
  const int lg   = lane >> 4;     // k-group
  const int b0   = blockIdx.x * 16;

  // ---------------- persistent recurrent weight fragments -> AGPRs ----------------
  // wave wid, tile n (= gate type): weight rows n*128 + wid*16 + lr
  u32x4 whh0[4][4], wih1[4][4], whh1[4][4];
  #pragma unroll
  for (int n = 0; n < 4; ++n)
    #pragma unroll
    for (int kk = 0; kk < 4; ++kk) {
      const int ro = (n*128 + wid*16 + lr)*128 + kk*32 + lg*8;
      const float* p0 = Whh0 + ro;
      const float* p1 = Wih1 + ro;
      const float* p2 = Whh1 + ro;
      bf16x8 f0, f1, f2;
      #pragma unroll
      for (int j = 0; j < 8; ++j) {
        f0[j] = (__bf16)p0[j];
        f1[j] = (__bf16)p1[j];
        f2[j] = (__bf16)p2[j];
      }
      whh0[n][kk] = __builtin_bit_cast(u32x4, f0);
      wih1[n][kk] = __builtin_bit_cast(u32x4, f1);
      whh1[n][kk] = __builtin_bit_cast(u32x4, f2);
    }
  // pin into AGPRs (144 AGPRs) so they never spill and never occupy arch VGPRs
  #pragma unroll
  for (int n = 0; n < 4; ++n)
    #pragma unroll
    for (int kk = 0; kk < 4; ++kk) {
      asm("" : "+a"(whh0[n][kk]));
      asm("" : "+a"(wih1[n][kk]));
      asm("" : "+a"(whh1[n][kk]));
    }

  // ---------------- fold phase: WT = Wproj^T (bf16) in sXf, then W0 = Wih0 @ Wproj ----------------
  {
    unsigned short* sWT = reinterpret_cast<unsigned short*>(sXf);  // [64 f][72 p] bf16
    int p  = tid >> 3;
    int f0 = (tid & 7) * 8;
    const float* src = Wproj + p*64 + f0;
    #pragma unroll
    for (int j = 0; j < 8; ++j) sWT[(f0 + j)*72 + p] = f2bf(src[j]);
  }
  BAR();
  {
    const unsigned short* sWT = reinterpret_cast<const unsigned short*>(sXf);
    #pragma unroll 1
    for (int mi = 0; mi < 4; ++mi) {
      int mt = wid*4 + mi;                       // 32 M-tiles over 512 gate rows
      f32x4 acc[4];
      #pragma unroll
      for (int n = 0; n < 4; ++n) acc[n] = f32x4{0.f,0.f,0.f,0.f};
      #pragma unroll
      for (int kk = 0; kk < 2; ++kk) {
        const float* a = Wih0 + (mt*16 + lr)*64 + kk*32 + lg*8;
        bf16x8 af;
        #pragma unroll
        for (int j = 0; j < 8; ++j) af[j] = (__bf16)a[j];
        #pragma unroll
        for (int nt = 0; nt < 4; ++nt) {
          bf16x8 bfr = *(const bf16x8*)&sWT[(nt*16 + lr)*72 + kk*32 + lg*8];
          acc[nt] = __builtin_amdgcn_mfma_f32_16x16x32_bf16(af, bfr, acc[nt], 0, 0, 0);
        }
      }
      #pragma unroll
      for (int nt = 0; nt < 4; ++nt)
        #pragma unroll
        for (int r = 0; r < 4; ++r)
          sW0[(mt*16 + lg*4 + r)*72 + nt*16 + lr] = f2bf(acc[nt][r]);
    }
  }
  // biases (fold b_proj through Wih0)
  {
    int g = tid;
    float a = 0.f;
    const float* wr = Wih0 + g*64;
    #pragma unroll 8
    for (int p = 0; p < 64; ++p) a += wr[p] * bproj[p];
    sB0[g] = bih0[g] + bhh0[g] + a;
    sB1[g] = bih1[g] + bhh1[g];
  }
  for (int i = tid; i < 16*136; i += 512) {
    sH0[0][i] = 0; sH0[1][i] = 0; sH1[0][i] = 0; sH1[1][i] = 0;
  }
  BAR();   // sW0 / sB / sH ready; sWT dead

  // W0 fragments -> AGPRs (80 more AGPRs; sW0 never read again in the loop)
  u32x4 w0f[2][4];
  #pragma unroll
  for (int kk = 0; kk < 2; ++kk)
    #pragma unroll
    for (int n = 0; n < 4; ++n)
      w0f[kk][n] = *(const u32x4*)&sW0[(n*128 + wid*16 + lr)*72 + kk*32 + lg*8];
  #pragma unroll
  for (int kk = 0; kk < 2; ++kk)
    #pragma unroll
    for (int n = 0; n < 4; ++n)
      asm("" : "+a"(w0f[kk][n]));

  // bias registers (per lane: its 4 gate-type columns)
  float b0r[4], b1r[4];
  #pragma unroll
  for (int n = 0; n < 4; ++n) {
    b0r[n] = sB0[n*128 + wid*16 + lr];
    b1r[n] = sB1[n*128 + wid*16 + lr];
  }

  // ---------------- x prefetch (pre-swizzled global source -> linear LDS), depth 2 ----------------
  const int schunk = (wid & 3)*64 + lane;          // 256 16B-chunks per tile
  const int xrow   = schunk >> 4;                  // 0..15
  const int xcc    = (schunk & 15) ^ (xrow & 7);   // swizzled source column chunk
  const float* xg  = x + ((size_t)(b0 + xrow) * 512) * 64 + xcc*4;  // t = 0
  if (wid < 4) {
    async16(xg, &sXf[0*1024 + wid*256]); xg += 64;   // t=0
    async16(xg, &sXf[1*1024 + wid*256]); xg += 64;   // t=1
    asm volatile("s_waitcnt vmcnt(1)" ::: "memory"); // t=0 landed
  }
  BAR();

  // fragment-read chunk offsets within an x buffer (conflict-free after swizzle)
  const int xo00 = lr*16 + ((lg*2 + 0) ^ (lr & 7));
  const int xo01 = lr*16 + ((lg*2 + 1) ^ (lr & 7));
  const int xo10 = lr*16 + ((8 + lg*2 + 0) ^ (lr & 7));
  const int xo11 = lr*16 + ((8 + lg*2 + 1) ^ (lr & 7));

  f32x4 c0r = {0.f,0.f,0.f,0.f}, c1r = {0.f,0.f,0.f,0.f};
  const int hcw = wid*16 + lr;            // this lane's h column
  int bufR = 0, bufW = 2;

  // ---------------- main time loop: 2 barriers / step ----------------
  #pragma unroll 1
  for (int t = 0; t < 512; ++t) {
    const int cur = t & 1;

    // prefetch x(t+2)
    if (wid < 4 && t < 510) { async16(xg, &sXf[bufW*1024 + wid*256]); xg += 64; }

    // ---- phase A: layer-0 gates + in-register pointwise ----
    f32x4 acc0[4];
    #pragma unroll
    for (int n = 0; n < 4; ++n) acc0[n] = f32x4{b0r[n], b0r[n], b0r[n], b0r[n]};

    const f32x4* xb = (const f32x4*)&sXf[bufR*1024];
    #pragma unroll
    for (int kk = 0; kk < 2; ++kk) {
      f32x4 a0 = xb[kk ? xo10 : xo00];
      f32x4 a1 = xb[kk ? xo11 : xo01];
      bf16x8 xa;
      #pragma unroll
      for (int j = 0; j < 4; ++j) { xa[j] = (__bf16)a0[j]; xa[4+j] = (__bf16)a1[j]; }
      #pragma unroll
      for (int n = 0; n < 4; ++n)
        acc0[n] = __builtin_amdgcn_mfma_f32_16x16x32_bf16(xa, asbf(w0f[kk][n]), acc0[n], 0, 0, 0);
    }
    #pragma unroll
    for (int kk = 0; kk < 4; ++kk) {
      bf16x8 ha = *(const bf16x8*)&sH0[cur][lr*136 + kk*32 + lg*8];
      #pragma unroll
      for (int n = 0; n < 4; ++n)
        acc0[n] = __builtin_amdgcn_mfma_f32_16x16x32_bf16(ha, asbf(whh0[n][kk]), acc0[n], 0, 0, 0);
    }
    #pragma unroll
    for (int r = 0; r < 4; ++r) {
      float iv = sigm(acc0[0][r]);
      float fv = sigm(acc0[1][r]);
      float gv = tanh_fast(acc0[2][r]);
      float ov = sigm(acc0[3][r]);
      float c  = fv * c0r[r] + iv * gv;
      c0r[r] = c;
      sH0[cur ^ 1][(lg*4 + r)*136 + hcw] = f2bf(ov * tanh_fast(c));
    }
    BAR();   // h0(t) visible

    // ---- phase B: layer-1 gates + in-register pointwise ----
    f32x4 acc1[4];
    #pragma unroll
    for (int n = 0; n < 4; ++n) acc1[n] = f32x4{b1r[n], b1r[n], b1r[n], b1r[n]};
    #pragma unroll
    for (int kk = 0; kk < 4; ++kk) {
      bf16x8 ha = *(const bf16x8*)&sH0[cur ^ 1][lr*136 + kk*32 + lg*8];
      #pragma unroll
      for (int n = 0; n < 4; ++n)
        acc1[n] = __builtin_amdgcn_mfma_f32_16x16x32_bf16(ha, asbf(wih1[n][kk]), acc1[n], 0, 0, 0);
    }
    #pragma unroll
    for (int kk = 0; kk < 4; ++kk) {
      bf16x8 ha = *(const bf16x8*)&sH1[cur][lr*136 + kk*32 + lg*8];
      #pragma unroll
      for (int n = 0; n < 4; ++n)
        acc1[n] = __builtin_amdgcn_mfma_f32_16x16x32_bf16(ha, asbf(whh1[n][kk]), acc1[n], 0, 0, 0);
    }
    #pragma unroll
    for (int r = 0; r < 4; ++r) {
      float iv = sigm(acc1[0][r]);
      float fv = sigm(acc1[1][r]);
      float gv = tanh_fast(acc1[2][r]);
      float ov = sigm(acc1[3][r]);
      float c  = fv * c1r[r] + iv * gv;
      c1r[r] = c;
      sH1[cur ^ 1][(lg*4 + r)*136 + hcw] = f2bf(ov * tanh_fast(c));
    }
    // drain x prefetch: need x(t+1) landed before next step reads it
    if (wid < 4) {
      if (t < 510) asm volatile("s_waitcnt vmcnt(1)" ::: "memory");
      else         asm volatile("s_waitcnt vmcnt(0)" ::: "memory");
    }
    BAR();   // h1(t) + x(t+1) visible

    bufR = (bufR == 2) ? 0 : bufR + 1;
    bufW = (bufW == 2) ? 0 : bufW + 1;
  }

  // ---------------- head: hid = relu(h1 @ Wh1^T + bh1); out = hid @ Wh2^T + bh2 ----------------
  // final h1 is in sH1[0] (t=511: cur=1, wrote buffer 0). Reuse sXf as f32 scratch [16][64].
  {
    int row = tid >> 5;          // 0..15
    int j0  = (tid & 31) * 2;    // 0..62
    float a0 = bh1[j0], a1 = bh1[j0 + 1];
    const float* w0 = Wh1 + j0*128;
    const float* w1 = w0 + 128;
    #pragma unroll 8
    for (int k = 0; k < 128; ++k) {
      float hv = bf2f(sH1[0][row*136 + k]);
      a0 += hv * w0[k];
      a1 += hv * w1[k];
    }
    sXf[row*64 + j0]     = fmaxf(a0, 0.f);
    sXf[row*64 + j0 + 1] = fmaxf(a1, 0.f);
  }
  BAR();
  if (tid < 16) {
    float a = bh2[0];
    #pragma unroll 8
    for (int j = 0; j < 64; ++j) a += sXf[tid*64 + j] * Wh2[j];
    out[b0 + tid] = a;
  }
}

extern "C" void kernel_launch(void* const* d_in, const int* in_sizes, int n_in,
                              void* d_out, int out_size, void* d_ws, size_t ws_size,
                              hipStream_t stream) {
  (void)in_sizes; (void)n_in; (void)d_ws; (void)ws_size; (void)out_size;
  const float* x     = (const float*)d_in[0];
  // d_in[1] = lengths (unused by reference)
  const float* Wproj = (const float*)d_in[2];
  const float* bproj = (const float*)d_in[3];
  const float* Wih0  = (const float*)d_in[4];
  const float* Whh0  = (const float*)d_in[5];
  const float* bih0  = (const float*)d_in[6];
  const float* bhh0  = (const float*)d_in[7];
  const float* Wih1  = (const float*)d_in[8];
  const float* Whh1  = (const float*)d_in[9];
  const float* bih1  = (const float*)d_in[10];
  const float* bhh1  = (const float*)d_in[11];
  const float* Wh1   = (const float*)d_in[12];
  const float* bh1   = (const float*)d_in[13];
  const float* Wh2   = (const float*)d_in[14];
  const float* bh2   = (const float*)d_in[15];
  float* out = (float*)d_out;

  hipLaunchKernelGGL(fraud_lstm_kernel, dim3(64), dim3(512), 0, stream,
                     x, Wproj, bproj, Wih0, Whh0, bih0, bhh0,
                     Wih1, Whh1, bih1, bhh1, Wh1, bh1, Wh2, bh2, out);
}

// Round 4
// 1257.614 us; speedup vs baseline: 2.2817x; 2.2817x over previous
//
#include <hip/hip_runtime.h>
#include <hip/hip_bf16.h>
#include <stdint.h>

typedef __bf16 bf16x8 __attribute__((ext_vector_type(8)));
typedef float  f32x4  __attribute__((ext_vector_type(4)));

#define BAR()  asm volatile("s_waitcnt lgkmcnt(0)\n\ts_barrier" ::: "memory")

static __device__ __forceinline__ float sigm(float x) {
  return __builtin_amdgcn_rcpf(1.0f + __builtin_amdgcn_exp2f(x * -1.4426950408889634f));
}
static __device__ __forceinline__ float tanh_fast(float x) {
  // tanh(x) = 1 - 2/(exp2(2x*log2e)+1); saturates correctly via exp2->inf/0
  return 1.0f - 2.0f * __builtin_amdgcn_rcpf(1.0f + __builtin_amdgcn_exp2f(x * 2.8853900817779268f));
}
static __device__ __forceinline__ unsigned short f2bf(float f) {
  return __builtin_bit_cast(unsigned short, (__bf16)f);
}
static __device__ __forceinline__ float bf2f(unsigned short u) {
  union { uint32_t i; float f; } v; v.i = ((uint32_t)u) << 16; return v.f;
}
static __device__ __forceinline__ void async16(const float* g, float* l) {
  __builtin_amdgcn_global_load_lds((__attribute__((address_space(1))) void*)g,
                                   (__attribute__((address_space(3))) void*)l, 16, 0, 0);
}

// Persistent fused kernel: 64 WGs x 512 threads; WG owns 16 batch rows for all
// 512 timesteps. Wave wid owns h-cols wid*16..wid*16+15, gate types i,f,g,o in
// its 4 MFMA N-tiles -> pointwise fully in registers.
// Register budget reality: 2 waves/SIMD => 256 unified regs/wave. Weights kept
// in regs: whh0(64) + wih1(64) + W0(32) = 160. Whh1 lives in LDS in a
// fragment-linear layout (ds_read_b128 at lane*16 -> zero bank conflicts).
// h state also stored fragment-linear (conflict-free A-operand reads).
__global__ __launch_bounds__(512) __attribute__((amdgpu_waves_per_eu(2, 2)))
void fraud_lstm_kernel(
    const float* __restrict__ x,     const float* __restrict__ Wproj,
    const float* __restrict__ bproj, const float* __restrict__ Wih0,
    const float* __restrict__ Whh0,  const float* __restrict__ bih0,
    const float* __restrict__ bhh0,  const float* __restrict__ Wih1,
    const float* __restrict__ Whh1,  const float* __restrict__ bih1,
    const float* __restrict__ bhh1,  const float* __restrict__ Wh1,
    const float* __restrict__ bh1,   const float* __restrict__ Wh2,
    const float* __restrict__ bh2,   float* __restrict__ out)
{
  // LDS total: 131072 + 8192 + 8192 + 12288 = 159744 B (< 160 KiB)
  __shared__ unsigned short sWf[65536];     // Whh1 frags [wid][n][kk][lane][8] bf16; reused as Wproj stage
  __shared__ unsigned short sH0f[2][2048];  // h0 dbuf, frag-linear [kk][lane][8] bf16
  __shared__ unsigned short sH1f[2][2048];  // h1 dbuf
  __shared__ float sXf[3*1024];             // x tile triple buffer (16 rows x 64 f32), chunk-swizzled

  const int tid  = threadIdx.x;
  const int lane = tid & 63;
  const int wid  = tid >> 6;      // 8 waves
  const int lr   = lane & 15;     // fragment row/col lane index
  const int lg   = lane >> 4;     // k-group
  const int b0   = blockIdx.x * 16;
  const int g0   = wid*16 + lr;   // this lane's h column (gate col within each gate type)

  // ---------------- stage Wproj (f32 [p=64][f=64]) into sWf ----------------
  {
    float* sWp = reinterpret_cast<float*>(sWf);
    for (int i = tid; i < 4096; i += 512) sWp[i] = Wproj[i];
  }
  BAR();

  // ---------------- fold W0[g][f] = sum_p Wih0[g][p]*Wproj[p][f]; fold biases ----------------
  float w0a[2][4][8];
  #pragma unroll
  for (int kk = 0; kk < 2; ++kk)
    #pragma unroll
    for (int n = 0; n < 4; ++n)
      #pragma unroll
      for (int j = 0; j < 8; ++j) w0a[kk][n][j] = 0.f;
  float bacc[4] = {0.f, 0.f, 0.f, 0.f};
  {
    const float* sWp = reinterpret_cast<const float*>(sWf);
    #pragma unroll 2
    for (int p = 0; p < 64; ++p) {
      float av[4];
      #pragma unroll
      for (int n = 0; n < 4; ++n) av[n] = Wih0[(n*128 + g0)*64 + p];
      float bp = bproj[p];
      #pragma unroll
      for (int n = 0; n < 4; ++n) bacc[n] += av[n] * bp;
      #pragma unroll
      for (int kk = 0; kk < 2; ++kk) {
        f32x4 wa = *(const f32x4*)&sWp[p*64 + kk*32 + lg*8];
        f32x4 wb = *(const f32x4*)&sWp[p*64 + kk*32 + lg*8 + 4];
        #pragma unroll
        for (int n = 0; n < 4; ++n)
          #pragma unroll
          for (int j = 0; j < 4; ++j) {
            w0a[kk][n][j]     += av[n] * wa[j];
            w0a[kk][n][4 + j] += av[n] * wb[j];
          }
      }
    }
  }
  bf16x8 w0f[2][4];
  #pragma unroll
  for (int kk = 0; kk < 2; ++kk)
    #pragma unroll
    for (int n = 0; n < 4; ++n)
      #pragma unroll
      for (int j = 0; j < 8; ++j) w0f[kk][n][j] = (__bf16)w0a[kk][n][j];

  float b0r[4], b1r[4];
  #pragma unroll
  for (int n = 0; n < 4; ++n) {
    const int g = n*128 + g0;
    b0r[n] = bih0[g] + bhh0[g] + bacc[n];
    b1r[n] = bih1[g] + bhh1[g];
  }
  BAR();   // everyone done reading the Wproj stage; sWf free for weight frags

  // ---------------- whh0, wih1 -> reg frags; whh1 -> LDS frag-linear ----------------
  bf16x8 whh0[4][4], wih1[4][4];
  #pragma unroll
  for (int n = 0; n < 4; ++n)
    #pragma unroll
    for (int kk = 0; kk < 4; ++kk) {
      const int ro = (n*128 + g0)*128 + kk*32 + lg*8;
      const float* p0 = Whh0 + ro;
      const float* p1 = Wih1 + ro;
      #pragma unroll
      for (int j = 0; j < 8; ++j) {
        whh0[n][kk][j] = (__bf16)p0[j];
        wih1[n][kk][j] = (__bf16)p1[j];
      }
    }
  #pragma unroll
  for (int n = 0; n < 4; ++n)
    #pragma unroll
    for (int kk = 0; kk < 4; ++kk) {
      const int ro = (n*128 + g0)*128 + kk*32 + lg*8;
      const float* p2 = Whh1 + ro;
      bf16x8 w;
      #pragma unroll
      for (int j = 0; j < 8; ++j) w[j] = (__bf16)p2[j];
      *(bf16x8*)&sWf[((wid*16 + n*4 + kk)*64 + lane)*8] = w;
    }

  // zero h buffers
  for (int i = tid; i < 2048; i += 512) {
    sH0f[0][i] = 0; sH0f[1][i] = 0; sH1f[0][i] = 0; sH1f[1][i] = 0;
  }

  // ---------------- x prefetch (pre-swizzled global source -> linear LDS), depth 2 ----------------
  const int schunk = (wid & 3)*64 + lane;          // 256 16B-chunks per tile
  const int xrow   = schunk >> 4;                  // 0..15
  const int xcc    = (schunk & 15) ^ (xrow & 7);   // swizzled source column chunk
  const float* xg  = x + ((size_t)(b0 + xrow) * 512) * 64 + xcc*4;  // t = 0
  if (wid < 4) {
    async16(xg, &sXf[0*1024 + wid*256]); xg += 64;   // t=0
    async16(xg, &sXf[1*1024 + wid*256]); xg += 64;   // t=1
    asm volatile("s_waitcnt vmcnt(1)" ::: "memory"); // t=0 landed
  }
  BAR();   // weight frags in LDS + h zeroed + x(0) landed

  // fragment-read chunk offsets within an x buffer (conflict-free after swizzle)
  const int xo00 = lr*16 + ((lg*2 + 0) ^ (lr & 7));
  const int xo01 = lr*16 + ((lg*2 + 1) ^ (lr & 7));
  const int xo10 = lr*16 + ((8 + lg*2 + 0) ^ (lr & 7));
  const int xo11 = lr*16 + ((8 + lg*2 + 1) ^ (lr & 7));

  // h write base for this lane's column (frag-linear): kk*512 + lgt*128 + row*8 + j
  const int hbase = (g0 >> 5)*512 + ((g0 >> 3) & 3)*128 + (g0 & 7);

  f32x4 c0r = {0.f,0.f,0.f,0.f}, c1r = {0.f,0.f,0.f,0.f};
  int bufR = 0, bufW = 2;

  // ---------------- main time loop: 2 barriers / step ----------------
  #pragma unroll 1
  for (int t = 0; t < 512; ++t) {
    const int cur = t & 1;

    // prefetch x(t+2)
    if (wid < 4 && t < 510) { async16(xg, &sXf[bufW*1024 + wid*256]); xg += 64; }

    // ---- phase A: layer-0 gates + in-register pointwise ----
    f32x4 acc0[4];
    #pragma unroll
    for (int n = 0; n < 4; ++n) acc0[n] = f32x4{b0r[n], b0r[n], b0r[n], b0r[n]};

    const f32x4* xb = (const f32x4*)&sXf[bufR*1024];
    #pragma unroll
    for (int kk = 0; kk < 2; ++kk) {
      f32x4 a0 = xb[kk ? xo10 : xo00];
      f32x4 a1 = xb[kk ? xo11 : xo01];
      bf16x8 xa;
      #pragma unroll
      for (int j = 0; j < 4; ++j) { xa[j] = (__bf16)a0[j]; xa[4+j] = (__bf16)a1[j]; }
      #pragma unroll
      for (int n = 0; n < 4; ++n)
        acc0[n] = __builtin_amdgcn_mfma_f32_16x16x32_bf16(xa, w0f[kk][n], acc0[n], 0, 0, 0);
    }
    #pragma unroll
    for (int kk = 0; kk < 4; ++kk) {
      bf16x8 ha = *(const bf16x8*)&sH0f[cur][(kk*64 + lane)*8];
      #pragma unroll
      for (int n = 0; n < 4; ++n)
        acc0[n] = __builtin_amdgcn_mfma_f32_16x16x32_bf16(ha, whh0[n][kk], acc0[n], 0, 0, 0);
    }
    #pragma unroll
    for (int r = 0; r < 4; ++r) {
      float iv = sigm(acc0[0][r]);
      float fv = sigm(acc0[1][r]);
      float gv = tanh_fast(acc0[2][r]);
      float ov = sigm(acc0[3][r]);
      float c  = fv * c0r[r] + iv * gv;
      c0r[r] = c;
      sH0f[cur ^ 1][hbase + (lg*4 + r)*8] = f2bf(ov * tanh_fast(c));
    }
    BAR();   // h0(t) visible

    // ---- phase B: layer-1 gates + in-register pointwise ----
    f32x4 acc1[4];
    #pragma unroll
    for (int n = 0; n < 4; ++n) acc1[n] = f32x4{b1r[n], b1r[n], b1r[n], b1r[n]};
    #pragma unroll
    for (int kk = 0; kk < 4; ++kk) {
      bf16x8 ha = *(const bf16x8*)&sH0f[cur ^ 1][(kk*64 + lane)*8];
      #pragma unroll
      for (int n = 0; n < 4; ++n)
        acc1[n] = __builtin_amdgcn_mfma_f32_16x16x32_bf16(ha, wih1[n][kk], acc1[n], 0, 0, 0);
    }
    #pragma unroll
    for (int kk = 0; kk < 4; ++kk) {
      bf16x8 ha = *(const bf16x8*)&sH1f[cur][(kk*64 + lane)*8];
      #pragma unroll
      for (int n = 0; n < 4; ++n) {
        bf16x8 wf = *(const bf16x8*)&sWf[((wid*16 + n*4 + kk)*64 + lane)*8];
        acc1[n] = __builtin_amdgcn_mfma_f32_16x16x32_bf16(ha, wf, acc1[n], 0, 0, 0);
      }
    }
    #pragma unroll
    for (int r = 0; r < 4; ++r) {
      float iv = sigm(acc1[0][r]);
      float fv = sigm(acc1[1][r]);
      float gv = tanh_fast(acc1[2][r]);
      float ov = sigm(acc1[3][r]);
      float c  = fv * c1r[r] + iv * gv;
      c1r[r] = c;
      sH1f[cur ^ 1][hbase + (lg*4 + r)*8] = f2bf(ov * tanh_fast(c));
    }
    // drain x prefetch: need x(t+1) landed before next step reads it
    if (wid < 4) {
      if (t < 510) asm volatile("s_waitcnt vmcnt(1)" ::: "memory");
      else         asm volatile("s_waitcnt vmcnt(0)" ::: "memory");
    }
    BAR();   // h1(t) + x(t+1) visible

    bufR = (bufR == 2) ? 0 : bufR + 1;
    bufW = (bufW == 2) ? 0 : bufW + 1;
  }

  // ---------------- head: hid = relu(h1 @ Wh1^T + bh1); out = hid @ Wh2^T + bh2 ----------------
  // final h1 is in sH1f[0] (t=511: cur=1, wrote buffer 0). Reuse sXf as f32 scratch [16][64].
  {
    int row = tid >> 5;          // 0..15
    int j0  = (tid & 31) * 2;    // 0..62
    float a0 = bh1[j0], a1 = bh1[j0 + 1];
    const float* w0 = Wh1 + j0*128;
    const float* w1 = w0 + 128;
    #pragma unroll 8
    for (int k = 0; k < 128; ++k) {
      float hv = bf2f(sH1f[0][(k >> 5)*512 + ((k >> 3) & 3)*128 + row*8 + (k & 7)]);
      a0 += hv * w0[k];
      a1 += hv * w1[k];
    }
    sXf[row*64 + j0]     = fmaxf(a0, 0.f);
    sXf[row*64 + j0 + 1] = fmaxf(a1, 0.f);
  }
  BAR();
  if (tid < 16) {
    float a = bh2[0];
    #pragma unroll 8
    for (int j = 0; j < 64; ++j) a += sXf[tid*64 + j] * Wh2[j];
    out[b0 + tid] = a;
  }
}

extern "C" void kernel_launch(void* const* d_in, const int* in_sizes, int n_in,
                              void* d_out, int out_size, void* d_ws, size_t ws_size,
                              hipStream_t stream) {
  (void)in_sizes; (void)n_in; (void)d_ws; (void)ws_size; (void)out_size;
  const float* x     = (const float*)d_in[0];
  // d_in[1] = lengths (unused by reference)
  const float* Wproj = (const float*)d_in[2];
  const float* bproj = (const float*)d_in[3];
  const float* Wih0  = (const float*)d_in[4];
  const float* Whh0  = (const float*)d_in[5];
  const float* bih0  = (const float*)d_in[6];
  const float* bhh0  = (const float*)d_in[7];
  const float* Wih1  = (const float*)d_in[8];
  const float* Whh1  = (const float*)d_in[9];
  const float* bih1  = (const float*)d_in[10];
  const float* bhh1  = (const float*)d_in[11];
  const float* Wh1   = (const float*)d_in[12];
  const float* bh1   = (const float*)d_in[13];
  const float* Wh2   = (const float*)d_in[14];
  const float* bh2   = (const float*)d_in[15];
  float* out = (float*)d_out;

  hipLaunchKernelGGL(fraud_lstm_kernel, dim3(64), dim3(512), 0, stream,
                     x, Wproj, bproj, Wih0, Whh0, bih0, bhh0,
                     Wih1, Whh1, bih1, bhh1, Wh1, bh1, Wh2, bh2, out);
}